// Round 10
// baseline (123.002 us; speedup 1.0000x reference)
//
#include <hip/hip_runtime.h>
#include <hip/hip_bf16.h>
#include <stdint.h>

#define NIMG 8
#define CIN  64
#define HWI  12544      // 112*112
#define NP   100352     // 8*12544
#define COUT 128

typedef short v8s __attribute__((ext_vector_type(8)));   // 8 bf16 (4 VGPRs)
typedef float v4f __attribute__((ext_vector_type(4)));   // 4 fp32 acc

// fake-quant to int grid: round(x*inv) clamped to [lo,hi]
static __device__ __forceinline__ int q8(float x, float inv, float lo, float hi) {
    float t = rintf(x * inv);
    t = fminf(fmaxf(t, lo), hi);
    return (int)t;
}

// funnel shift: bytes of ({hi,lo} >> sh) — compiler emits v_alignbit_b32
static __device__ __forceinline__ uint32_t funnel(uint32_t hi, uint32_t lo, int sh) {
    return (uint32_t)(((((uint64_t)hi) << 32) | (uint64_t)lo) >> sh);
}

// manual signed-byte dot4
static __device__ __forceinline__ int dot4(uint32_t a, uint32_t b, int c) {
    int acc = c;
    #pragma unroll
    for (int i = 0; i < 4; ++i)
        acc += (int)(int8_t)(a >> (8*i)) * (int)(int8_t)(b >> (8*i));
    return acc;
}

// exact int -> bf16 bits (|v| <= 256 fits in 8 significand bits)
static __device__ __forceinline__ uint16_t i2bf(int v) {
    union { float f; uint32_t u; } c; c.f = (float)v;
    return (uint16_t)(c.u >> 16);
}

// ---------------------------------------------------------------------------
// Single fused kernel:
//   reg:  quantize this thread's A-fragment weights (w2q / wscq -> bf16)
//   ph1:  x -> int8 quant -> LDS tile   (4 halo rows x 64 ch x 112)
//   ph2:  depthwise 3x3 int + relu-quant -> LDS Bl [224 px][132 B]
//   ph3:  MFMA GEMM (conv2 + shortcut) + requant epilogue -> fp32 out
// Block = (n, 2 output rows) = 448 blocks x 256 threads.
// LDS = 29952 (tile) + 29568 (Bl) = 59520 B -> 2 blocks/CU.
// ---------------------------------------------------------------------------
__global__ void __launch_bounds__(256) fused_kernel(
    const float* __restrict__ x, const float* __restrict__ w1,
    const float* __restrict__ w2, const float* __restrict__ wsc,
    const float* __restrict__ sinp, const float* __restrict__ srelup,
    const float* __restrict__ saddp, const float* __restrict__ sw1p,
    const float* __restrict__ sw2p, const float* __restrict__ swscp,
    float* __restrict__ out)
{
    __shared__ int8_t tile[64 * 468];   // 29952 B
    __shared__ int8_t Bl[224 * 132];    // 29568 B

    int bid = blockIdx.x;
    int n = bid / 56, ht = bid - n*56, hb = ht*2;
    int tid = threadIdx.x;
    int wave = tid >> 6, lane = tid & 63;
    int lr = lane >> 4, ln = lane & 15;
    float sin_f = sinp[0];
    float inv_sin = 1.0f / sin_f;

    // ---- phase 0: quantize A-fragment weights into registers (bf16 ints) ----
    // a[mi][seg]: m = (wave*2+mi)*16 + ln ; k = seg*32 + lr*8 + j
    // segs 0..1 from w2 (k<64), segs 2..3 from wsc (k-64)
    v8s a[2][4];
    {
        float inv2 = 1.0f / sw2p[0];
        float invs = 1.0f / swscp[0];
        #pragma unroll
        for (int mi = 0; mi < 2; ++mi) {
            int m = (wave*2 + mi)*16 + ln;
            #pragma unroll
            for (int hs = 0; hs < 2; ++hs) {
                const float* src = hs ? wsc : w2;
                float inv = hs ? invs : inv2;
                #pragma unroll
                for (int s2 = 0; s2 < 2; ++s2) {
                    float4 f0 = *(const float4*)(src + m*64 + s2*32 + lr*8);
                    float4 f1 = *(const float4*)(src + m*64 + s2*32 + lr*8 + 4);
                    float fv[8] = {f0.x,f0.y,f0.z,f0.w,f1.x,f1.y,f1.z,f1.w};
                    v8s t;
                    #pragma unroll
                    for (int e = 0; e < 8; ++e) {
                        float q = rintf(fv[e] * inv);
                        q = fminf(fmaxf(q, -128.f), 127.f);
                        union { float f; uint32_t u; } c; c.f = q;
                        t[e] = (short)(c.u >> 16);   // exact: integral, |q|<=128
                    }
                    a[mi][hs*2 + s2] = t;
                }
            }
        }
    }

    // ---- phase 1: stage + quantize 4 halo rows x 64 ch x 112 into tile ----
    for (int i = 0; i < 28; ++i) {
        int id = tid + i*256;
        int c = id / 112; int rem = id - c*112;
        int r = rem / 28; int seg = rem - r*28;
        int grow = hb + r - 1;
        float4 v = make_float4(0.f, 0.f, 0.f, 0.f);
        if ((unsigned)grow < 112u)
            v = *(const float4*)(x + ((size_t)(n*64 + c) * HWI + grow*112 + seg*4));
        float vv[4] = {v.x, v.y, v.z, v.w};
        uint32_t pk = 0;
        #pragma unroll
        for (int e = 0; e < 4; ++e) {
            int q = q8(vv[e], inv_sin, -128.0f, 127.0f);
            pk |= (uint32_t)(q & 255) << (8*e);
        }
        *(uint32_t*)&tile[c*468 + r*116 + seg*4] = pk;
    }
    {
        int c = tid >> 2, r = tid & 3;
        *(uint32_t*)&tile[c*468 + r*116 + 112] = 0;
    }
    __syncthreads();

    // ---- phase 2: depthwise 3x3 + relu-quant; write yq/xq bytes into Bl ----
    {
        int rsel = wave >> 1;             // which of the 2 output rows
        int half = wave & 1;              // which half of the 112-wide row
        int c = lane;

        float isw1 = 1.0f / sw1p[0];
        uint32_t wp[3];
        #pragma unroll
        for (int ky = 0; ky < 3; ++ky) {
            uint32_t pk = 0;
            #pragma unroll
            for (int kx = 0; kx < 3; ++kx) {
                int q = q8(w1[c*9 + ky*3 + kx], isw1, -128.0f, 127.0f);
                pk |= (uint32_t)(q & 255) << (8*kx);
            }
            wp[ky] = pk;
        }
        float r1 = (sin_f * sw1p[0]) / srelup[0];

        int base[3];
        #pragma unroll
        for (int r2 = 0; r2 < 3; ++r2) base[r2] = c*468 + (rsel + r2)*116;
        int w0b = 56*half;

        uint32_t Ar[3], Br[3], Cr[3];
        #pragma unroll
        for (int r2 = 0; r2 < 3; ++r2) {
            Ar[r2] = half ? *(uint32_t*)&tile[base[r2] + w0b - 4] : 0u;
            Br[r2] = *(uint32_t*)&tile[base[r2] + w0b];
            Cr[r2] = *(uint32_t*)&tile[base[r2] + w0b + 4];
        }

        for (int q = 0; q < 14; ++q) {
            int acc0 = 0, acc1 = 0, acc2 = 0, acc3 = 0;
            #pragma unroll
            for (int r2 = 0; r2 < 3; ++r2) {
                uint32_t d0 = funnel(Br[r2], Ar[r2], 24);
                uint32_t d1 = Br[r2];
                uint32_t d2 = funnel(Cr[r2], Br[r2], 8);
                uint32_t d3 = funnel(Cr[r2], Br[r2], 16);
                acc0 = dot4(d0, wp[r2], acc0);
                acc1 = dot4(d1, wp[r2], acc1);
                acc2 = dot4(d2, wp[r2], acc2);
                acc3 = dot4(d3, wp[r2], acc3);
            }
            int accs[4] = {acc0, acc1, acc2, acc3};
            uint32_t xdw = Br[1];
            int pxb = rsel*112 + w0b + q*4;
            #pragma unroll
            for (int j = 0; j < 4; ++j) {
                float t = rintf((float)accs[j] * r1);
                t = fminf(fmaxf(t, 0.0f), 255.0f);
                Bl[(pxb + j)*132 + c]      = (int8_t)(int)t;                 // yq
                Bl[(pxb + j)*132 + 64 + c] = (int8_t)((xdw >> (8*j)) & 255); // xq
            }
            #pragma unroll
            for (int r2 = 0; r2 < 3; ++r2) { Ar[r2] = Br[r2]; Br[r2] = Cr[r2]; }
            if (q < 13) {
                #pragma unroll
                for (int r2 = 0; r2 < 3; ++r2)
                    Cr[r2] = *(uint32_t*)&tile[base[r2] + w0b + q*4 + 8];
            }
        }
    }
    __syncthreads();

    // ---- phase 3: GEMM (mfma_f32_16x16x32_bf16) + requant epilogue ----
    {
        float S2  = sw2p[0] * srelup[0];
        float Ssc = swscp[0] * sinp[0];
        float sadd = saddp[0];
        float inv_sadd = 1.0f / sadd;

        size_t orow = (size_t)n*COUT*HWI + (size_t)hb*112;

        for (int nt = 0; nt < 14; ++nt) {
            int boff = (nt*16 + ln)*132 + lr*8;
            v8s bf[4];
            #pragma unroll
            for (int seg = 0; seg < 4; ++seg) {
                uint32_t d0 = *(const uint32_t*)&Bl[boff + seg*32];
                uint32_t d1 = *(const uint32_t*)&Bl[boff + seg*32 + 4];
                v8s t;
                if (seg < 2) {
                    #pragma unroll
                    for (int e = 0; e < 4; ++e) {
                        t[e]     = (short)i2bf((int)((d0 >> (8*e)) & 255u));
                        t[4 + e] = (short)i2bf((int)((d1 >> (8*e)) & 255u));
                    }
                } else {
                    #pragma unroll
                    for (int e = 0; e < 4; ++e) {
                        t[e]     = (short)i2bf((int)(int8_t)(d0 >> (8*e)));
                        t[4 + e] = (short)i2bf((int)(int8_t)(d1 >> (8*e)));
                    }
                }
                bf[seg] = t;
            }
            #pragma unroll
            for (int mi = 0; mi < 2; ++mi) {
                v4f acc2 = {0.f, 0.f, 0.f, 0.f};
                v4f accs = {0.f, 0.f, 0.f, 0.f};
                acc2 = __builtin_amdgcn_mfma_f32_16x16x32_bf16(a[mi][0], bf[0], acc2, 0, 0, 0);
                acc2 = __builtin_amdgcn_mfma_f32_16x16x32_bf16(a[mi][1], bf[1], acc2, 0, 0, 0);
                accs = __builtin_amdgcn_mfma_f32_16x16x32_bf16(a[mi][2], bf[2], accs, 0, 0, 0);
                accs = __builtin_amdgcn_mfma_f32_16x16x32_bf16(a[mi][3], bf[3], accs, 0, 0, 0);
                size_t obase = orow + (size_t)((wave*2 + mi)*16 + lr*4)*HWI + nt*16 + ln;
                #pragma unroll
                for (int r = 0; r < 4; ++r) {
                    float v = S2 * acc2[r] + Ssc * accs[r];
                    float t = rintf(v * inv_sadd);
                    t = fminf(fmaxf(t, -128.0f), 127.0f);
                    out[obase + (size_t)r*HWI] = t * sadd;
                }
            }
        }
    }
}

// ---------------------------------------------------------------------------
extern "C" void kernel_launch(void* const* d_in, const int* in_sizes, int n_in,
                              void* d_out, int out_size, void* d_ws, size_t ws_size,
                              hipStream_t stream) {
    const float* x     = (const float*)d_in[0];
    const float* w1    = (const float*)d_in[1];
    const float* w2    = (const float*)d_in[2];
    const float* wsc   = (const float*)d_in[3];
    const float* sin   = (const float*)d_in[4];
    const float* srelu = (const float*)d_in[5];
    const float* sadd  = (const float*)d_in[6];
    const float* sw1   = (const float*)d_in[7];
    const float* sw2   = (const float*)d_in[8];
    const float* swsc  = (const float*)d_in[9];

    fused_kernel<<<NIMG * 56, 256, 0, stream>>>(x, w1, w2, wsc,
                                                sin, srelu, sadd, sw1, sw2, swsc,
                                                (float*)d_out);
}

// Round 11
// 122.323 us; speedup vs baseline: 1.0056x; 1.0056x over previous
//
#include <hip/hip_runtime.h>
#include <hip/hip_bf16.h>
#include <stdint.h>

#define NIMG 8
#define CIN  64
#define HWI  12544      // 112*112
#define COUT 128

typedef short v8s __attribute__((ext_vector_type(8)));   // 8 bf16 (4 VGPRs)
typedef float v4f __attribute__((ext_vector_type(4)));   // 4 fp32 acc

// fake-quant to int grid: round(x*inv) clamped to [lo,hi]
static __device__ __forceinline__ int q8(float x, float inv, float lo, float hi) {
    float t = rintf(x * inv);
    t = fminf(fmaxf(t, lo), hi);
    return (int)t;
}

// funnel shift: bytes of ({hi,lo} >> sh) — compiler emits v_alignbit_b32
static __device__ __forceinline__ uint32_t funnel(uint32_t hi, uint32_t lo, int sh) {
    return (uint32_t)(((((uint64_t)hi) << 32) | (uint64_t)lo) >> sh);
}

// manual signed-byte dot4
static __device__ __forceinline__ int dot4(uint32_t a, uint32_t b, int c) {
    int acc = c;
    #pragma unroll
    for (int i = 0; i < 4; ++i)
        acc += (int)(int8_t)(a >> (8*i)) * (int)(int8_t)(b >> (8*i));
    return acc;
}

// exact int -> bf16 bits (|v| <= 256 fits in 8 significand bits)
static __device__ __forceinline__ uint16_t i2bf(int v) {
    union { float f; uint32_t u; } c; c.f = (float)v;
    return (uint16_t)(c.u >> 16);
}

// ---------------------------------------------------------------------------
// K0: quantize 1x1 weights into bf16 matrix [128 co][128 k] in ws
//     k<64: w2q ; k>=64: wscq.  8 blocks, coalesced float4 loads.
// ---------------------------------------------------------------------------
__global__ void __launch_bounds__(256) wprep_kernel(
    const float* __restrict__ w2, const float* __restrict__ wsc,
    const float* __restrict__ sw2p, const float* __restrict__ swscp,
    uint16_t* __restrict__ wbuf)
{
    int t = blockIdx.x * 256 + threadIdx.x;   // 2048 threads, 4 weights each
    int f = t * 4;
    int co = f >> 6, k = f & 63;
    float inv2 = 1.0f / sw2p[0];
    float invs = 1.0f / swscp[0];
    float4 a = *(const float4*)(w2 + f);
    float4 b = *(const float4*)(wsc + f);
    float av[4] = {a.x, a.y, a.z, a.w};
    float bv[4] = {b.x, b.y, b.z, b.w};
    uint16_t* d2 = wbuf + co*128 + k;
    uint16_t* ds = wbuf + co*128 + 64 + k;
    *(ushort2*)(d2)     = make_ushort2(i2bf(q8(av[0], inv2, -128.f, 127.f)),
                                       i2bf(q8(av[1], inv2, -128.f, 127.f)));
    *(ushort2*)(d2 + 2) = make_ushort2(i2bf(q8(av[2], inv2, -128.f, 127.f)),
                                       i2bf(q8(av[3], inv2, -128.f, 127.f)));
    *(ushort2*)(ds)     = make_ushort2(i2bf(q8(bv[0], invs, -128.f, 127.f)),
                                       i2bf(q8(bv[1], invs, -128.f, 127.f)));
    *(ushort2*)(ds + 2) = make_ushort2(i2bf(q8(bv[2], invs, -128.f, 127.f)),
                                       i2bf(q8(bv[3], invs, -128.f, 127.f)));
}

// ---------------------------------------------------------------------------
// K1 (fused, 1 output row / block, 896 blocks):
//   ph1: x rows h-1..h+1 -> int8 quant -> LDS tile [64 c][3 r][116]
//   ph2: depthwise 3x3 int + relu-quant -> LDS Bl bf16 [112 px][136]
//        (k 0..63 = yq, 64..127 = xq — exact small ints in bf16)
//   ph3: MFMA GEMM (conv2 + shortcut), B via direct ds_read_b128, fp32 out
// LDS = 22272 + 30464 = 52736 B -> 3 blocks/CU (12 waves/CU).
// ---------------------------------------------------------------------------
__global__ void __launch_bounds__(256) fused_kernel(
    const float* __restrict__ x, const float* __restrict__ w1,
    const uint16_t* __restrict__ wbuf,
    const float* __restrict__ sinp, const float* __restrict__ srelup,
    const float* __restrict__ saddp, const float* __restrict__ sw1p,
    const float* __restrict__ sw2p, const float* __restrict__ swscp,
    float* __restrict__ out)
{
    __shared__ int8_t   tile[64 * 348];   // c-stride 348 B (87 dwords, odd)
    __shared__ uint16_t Bl[112 * 136];    // px-stride 272 B (16B-aligned for b128)

    int bid = blockIdx.x;
    int n = bid / 112, h = bid - n*112;
    int tid = threadIdx.x;
    int wave = tid >> 6, lane = tid & 63;
    int lr = lane >> 4, ln = lane & 15;
    float sin_f = sinp[0];
    float inv_sin = 1.0f / sin_f;

    // ---- phase 1: stage + quantize 3 halo rows x 64 ch x 112 into tile ----
    // 64c * 3r * 28seg = 5376 float4 loads, 21 per thread
    for (int i = 0; i < 21; ++i) {
        int id = tid + i*256;
        int c = id / 84; int rem = id - c*84;
        int r = rem / 28; int seg = rem - r*28;
        int grow = h + r - 1;
        float4 v = make_float4(0.f, 0.f, 0.f, 0.f);
        if ((unsigned)grow < 112u)
            v = *(const float4*)(x + ((size_t)(n*64 + c) * HWI + grow*112 + seg*4));
        float vv[4] = {v.x, v.y, v.z, v.w};
        uint32_t pk = 0;
        #pragma unroll
        for (int e = 0; e < 4; ++e) {
            int q = q8(vv[e], inv_sin, -128.0f, 127.0f);
            pk |= (uint32_t)(q & 255) << (8*e);
        }
        *(uint32_t*)&tile[c*348 + r*116 + seg*4] = pk;
    }
    if (tid < 192) {  // zero pad cols 112..115 of each (c, r)
        int c = tid / 3, r = tid - c*3;
        *(uint32_t*)&tile[c*348 + r*116 + 112] = 0;
    }
    __syncthreads();

    // ---- phase 2: depthwise 3x3 + relu-quant; write bf16 yq/xq into Bl ----
    {
        int c = lane;
        int w0b = wave * 28;              // 28-px quarter of the row (4-aligned)

        float isw1 = 1.0f / sw1p[0];
        uint32_t wp[3];
        #pragma unroll
        for (int ky = 0; ky < 3; ++ky) {
            uint32_t pk = 0;
            #pragma unroll
            for (int kx = 0; kx < 3; ++kx) {
                int q = q8(w1[c*9 + ky*3 + kx], isw1, -128.0f, 127.0f);
                pk |= (uint32_t)(q & 255) << (8*kx);
            }
            wp[ky] = pk;
        }
        float r1 = (sin_f * sw1p[0]) / srelup[0];

        int base[3];
        #pragma unroll
        for (int r2 = 0; r2 < 3; ++r2) base[r2] = c*348 + r2*116;

        uint32_t Ar[3], Br[3], Cr[3];
        #pragma unroll
        for (int r2 = 0; r2 < 3; ++r2) {
            Ar[r2] = wave ? *(uint32_t*)&tile[base[r2] + w0b - 4] : 0u;
            Br[r2] = *(uint32_t*)&tile[base[r2] + w0b];
            Cr[r2] = *(uint32_t*)&tile[base[r2] + w0b + 4];
        }

        for (int q = 0; q < 7; ++q) {
            int acc0 = 0, acc1 = 0, acc2 = 0, acc3 = 0;
            #pragma unroll
            for (int r2 = 0; r2 < 3; ++r2) {
                uint32_t d0 = funnel(Br[r2], Ar[r2], 24);
                uint32_t d1 = Br[r2];
                uint32_t d2 = funnel(Cr[r2], Br[r2], 8);
                uint32_t d3 = funnel(Cr[r2], Br[r2], 16);
                acc0 = dot4(d0, wp[r2], acc0);
                acc1 = dot4(d1, wp[r2], acc1);
                acc2 = dot4(d2, wp[r2], acc2);
                acc3 = dot4(d3, wp[r2], acc3);
            }
            int accs[4] = {acc0, acc1, acc2, acc3};
            uint32_t xdw = Br[1];             // xq bytes (row h) for these 4 px
            int pxb = w0b + q*4;
            #pragma unroll
            for (int j = 0; j < 4; ++j) {
                float t = rintf((float)accs[j] * r1);
                t = fminf(fmaxf(t, 0.0f), 255.0f);
                int xv = (int)(int8_t)((xdw >> (8*j)) & 255);
                Bl[(pxb + j)*136 + c]      = i2bf((int)t);   // yq
                Bl[(pxb + j)*136 + 64 + c] = i2bf(xv);       // xq
            }
            #pragma unroll
            for (int r2 = 0; r2 < 3; ++r2) { Ar[r2] = Br[r2]; Br[r2] = Cr[r2]; }
            if (q < 6) {
                #pragma unroll
                for (int r2 = 0; r2 < 3; ++r2)
                    Cr[r2] = *(uint32_t*)&tile[base[r2] + w0b + q*4 + 8];
            }
        }
    }
    __syncthreads();

    // ---- phase 3: GEMM (mfma_f32_16x16x32_bf16) + requant epilogue ----
    {
        float S2  = sw2p[0] * srelup[0];
        float Ssc = swscp[0] * sinp[0];
        float sadd = saddp[0];
        float inv_sadd = 1.0f / sadd;

        // A fragments: m = (wave*2+mi)*16 + ln, k = seg*32 + lr*8 + j
        v8s a[2][4];
        #pragma unroll
        for (int mi = 0; mi < 2; ++mi) {
            int m = (wave*2 + mi)*16 + ln;
            #pragma unroll
            for (int seg = 0; seg < 4; ++seg)
                a[mi][seg] = *(const v8s*)(wbuf + (size_t)m*128 + seg*32 + lr*8);
        }

        size_t orow = (size_t)n*COUT*HWI + (size_t)h*112;

        for (int nt = 0; nt < 7; ++nt) {
            int boff = (nt*16 + ln)*136 + lr*8;
            v8s bf[4];
            #pragma unroll
            for (int seg = 0; seg < 4; ++seg)
                bf[seg] = *(const v8s*)&Bl[boff + seg*32];   // direct b128 reads
            #pragma unroll
            for (int mi = 0; mi < 2; ++mi) {
                v4f acc2 = {0.f, 0.f, 0.f, 0.f};
                v4f accs = {0.f, 0.f, 0.f, 0.f};
                acc2 = __builtin_amdgcn_mfma_f32_16x16x32_bf16(a[mi][0], bf[0], acc2, 0, 0, 0);
                acc2 = __builtin_amdgcn_mfma_f32_16x16x32_bf16(a[mi][1], bf[1], acc2, 0, 0, 0);
                accs = __builtin_amdgcn_mfma_f32_16x16x32_bf16(a[mi][2], bf[2], accs, 0, 0, 0);
                accs = __builtin_amdgcn_mfma_f32_16x16x32_bf16(a[mi][3], bf[3], accs, 0, 0, 0);
                size_t obase = orow + (size_t)((wave*2 + mi)*16 + lr*4)*HWI + nt*16 + ln;
                #pragma unroll
                for (int r = 0; r < 4; ++r) {
                    float v = S2 * acc2[r] + Ssc * accs[r];
                    float t = rintf(v * inv_sadd);
                    t = fminf(fmaxf(t, -128.0f), 127.0f);
                    out[obase + (size_t)r*HWI] = t * sadd;
                }
            }
        }
    }
}

// ---------------------------------------------------------------------------
extern "C" void kernel_launch(void* const* d_in, const int* in_sizes, int n_in,
                              void* d_out, int out_size, void* d_ws, size_t ws_size,
                              hipStream_t stream) {
    const float* x     = (const float*)d_in[0];
    const float* w1    = (const float*)d_in[1];
    const float* w2    = (const float*)d_in[2];
    const float* wsc   = (const float*)d_in[3];
    const float* sin   = (const float*)d_in[4];
    const float* srelu = (const float*)d_in[5];
    const float* sadd  = (const float*)d_in[6];
    const float* sw1   = (const float*)d_in[7];
    const float* sw2   = (const float*)d_in[8];
    const float* swsc  = (const float*)d_in[9];

    uint16_t* wbuf = (uint16_t*)d_ws;   // 32 KB bf16 weight matrix

    wprep_kernel<<<8, 256, 0, stream>>>(w2, wsc, sw2, swsc, wbuf);
    fused_kernel<<<NIMG * 112, 256, 0, stream>>>(x, w1, wbuf,
                                                 sin, srelu, sadd, sw1, sw2, swsc,
                                                 (float*)d_out);
}